// Round 10
// baseline (417.479 us; speedup 1.0000x reference)
//
#include <hip/hip_runtime.h>

// BiLSTM (diagonal, PixelRNN-style) on MI355X.
// R9: R8's persistent scan + fine-grained LLC ring protocol, with the per-lane
// critical path halved: 512-thread blocks (8 waves; two waves-sets split the
// m-tiles of each phase) -> 16 waves/CU, and exp2-space gate math (weights,
// biases, hmap prescaled by log2e; lc kept scaled by 2*log2e) so every
// transcendental is a bare v_exp_f32.

using bf16   = __bf16;
using bf16x8 = __attribute__((ext_vector_type(8))) __bf16;
using f32x4  = __attribute__((ext_vector_type(4))) float;

#define SCOPE_AGENT __HIP_MEMORY_SCOPE_AGENT
#define LOG2E 1.4426950408889634f
#define K2E   2.8853900817779268f  // 2*log2e

__device__ __forceinline__ bf16x8 bzero8() {
  bf16x8 v;
#pragma unroll
  for (int e = 0; e < 8; ++e) v[e] = (bf16)0.0f;
  return v;
}
__device__ __forceinline__ unsigned short f2bu(float f) {
  bf16 b = (bf16)f;
  return __builtin_bit_cast(unsigned short, b);
}
__device__ __forceinline__ float bu2f(unsigned short u) {
  return __uint_as_float(((unsigned)u) << 16);
}

// ---------------- prep: weights -> bf16, [n][k] layouts ----------------
// WnL/WnR are prescaled by log2e (gate math runs in exp2 space).
__global__ void prep_kernel(const float* __restrict__ w_i2s,
                            const float* __restrict__ w_left,
                            const float* __restrict__ w_right,
                            const float* __restrict__ w_skip,
                            bf16* __restrict__ WnI, bf16* __restrict__ WnL,
                            bf16* __restrict__ WnR, bf16* __restrict__ WnS) {
  int t = blockIdx.x * 256 + threadIdx.x;
  if (t < 32768) {
    WnI[t] = (bf16)w_i2s[t];  // [256][128] o-major == desired [n][k]
    int o = t >> 7, k = t & 127;
    int src = (k < 64) ? (o * 128 + k * 2) : (o * 128 + (k - 64) * 2 + 1);
    WnL[t] = (bf16)(w_left[src] * LOG2E);
    WnR[t] = (bf16)(w_right[src] * LOG2E);
    if (t < 8192) WnS[t] = (bf16)w_skip[t];  // [128][64]
  }
}

// ------- hmap2 = pack(log2e * (x @ w_i2s^T)) : [p][c] ushort4 -------
__global__ __launch_bounds__(256, 2)
void hmap_kernel(const float* __restrict__ x, const bf16* __restrict__ Wn,
                 ushort4* __restrict__ hmap2) {
  __shared__ __align__(16) bf16 At[64 * 128];  // XOR-swizzled
  const int tile = blockIdx.x;
  const int b = tile >> 4, h0 = (tile & 15) << 1;
  const int t = threadIdx.x;
  const float* xb = x + (size_t)(b * 128) * 1024 + h0 * 32;
#pragma unroll
  for (int i = 0; i < 8; ++i) {
    int idx = t + 256 * i;          // [0,2048)
    int cc = idx >> 4, m4 = idx & 15;
    f32x4 v = *(const f32x4*)(xb + (size_t)cc * 1024 + m4 * 4);
#pragma unroll
    for (int e = 0; e < 4; ++e) {
      int m = m4 * 4 + e;
      int kb = (cc * 2) ^ ((m & 7) << 4);
      *(bf16*)((char*)At + m * 256 + kb) = (bf16)v[e];
    }
  }
  __syncthreads();
  const int wv = t >> 6, l = t & 63;
  const int l15 = l & 15, lq = l >> 4;
  const int c = wv * 16 + l15;
  bf16x8 bfrag[4][4];
#pragma unroll
  for (int q = 0; q < 4; ++q)
#pragma unroll
    for (int kk = 0; kk < 4; ++kk)
      bfrag[q][kk] = *(const bf16x8*)(Wn + (q * 64 + c) * 128 + kk * 32 + lq * 8);
  f32x4 acc[4][4];
  const f32x4 fz = {0.f, 0.f, 0.f, 0.f};
#pragma unroll
  for (int ms = 0; ms < 4; ++ms)
#pragma unroll
    for (int q = 0; q < 4; ++q) acc[ms][q] = fz;
#pragma unroll
  for (int kk = 0; kk < 4; ++kk) {
#pragma unroll
    for (int ms = 0; ms < 4; ++ms) {
      int m = ms * 16 + l15;
      int kb = ((kk * 32 + lq * 8) * 2) ^ ((m & 7) << 4);
      bf16x8 a = *(const bf16x8*)((const char*)At + m * 256 + kb);
#pragma unroll
      for (int q = 0; q < 4; ++q)
        acc[ms][q] =
            __builtin_amdgcn_mfma_f32_16x16x32_bf16(a, bfrag[q][kk], acc[ms][q], 0, 0, 0);
    }
  }
  const int pix0 = tile * 64;
#pragma unroll
  for (int ms = 0; ms < 4; ++ms)
#pragma unroll
    for (int j = 0; j < 4; ++j) {
      int p = pix0 + ms * 16 + lq * 4 + j;
      ushort4 hv;
      hv.x = f2bu(acc[ms][0][j] * LOG2E);
      hv.y = f2bu(acc[ms][1][j] * LOG2E);
      hv.z = f2bu(acc[ms][2][j] * LOG2E);
      hv.w = f2bu(acc[ms][3][j] * LOG2E);
      hmap2[(size_t)p * 64 + c] = hv;
    }
}

// ---------------- persistent scan: all 32 steps, 8-wave blocks ----------------
// blk = tl*32 + q, q = batch*2 + stream. Block owns rows {2tl, 2tl+1}.
// 8 waves: wave w -> channel group (w&3), m-half (w>>2).
// Phase A: tile ms = 2+(w>>2) (row r0+1, no halo) + publish; phase B: ms = w>>2.
__global__ __launch_bounds__(512, 4)
void scan_kernel(bf16* __restrict__ lhLout, bf16* __restrict__ lhRout,
                 const ushort4* __restrict__ hmap2,
                 const bf16* __restrict__ WnL, const bf16* __restrict__ WnR,
                 const float* __restrict__ bL, const float* __restrict__ bR,
                 bf16* __restrict__ ring, unsigned* __restrict__ prodFlag,
                 unsigned* __restrict__ consFlag) {
  __shared__ __align__(16) bf16 buf[2][3 * 32 * 64];  // 2 x 12 KB
  const int blk = blockIdx.x;
  const int q = blk & 31, tl = blk >> 5;
  const bool right = (q & 1) != 0;
  const int b = q >> 1;
  const int r0 = tl * 2;
  const int t = threadIdx.x;
  const int dw = right ? 1 : -1;
  bf16* __restrict__ lout = right ? lhRout : lhLout;
  const bf16* __restrict__ Wn = right ? WnR : WnL;
  const float* __restrict__ bias = right ? bR : bL;
  const int w8 = t >> 6, l = t & 63, l15 = l & 15, lq = l >> 4;
  const int wv = w8 & 3, mhalf = w8 >> 2;
  const int c = wv * 16 + l15;   // channel this lane owns
  const int wb_ = mhalf * 16;    // px half this wave owns

  // zero buf[0] fully + buf[1] row0
#pragma unroll
  for (int i = 0; i < 2; ++i) {
    int idx = t + 512 * i;
    if (idx < 768) ((bf16x8*)buf[0])[idx] = bzero8();
  }
  if (t < 256) ((bf16x8*)buf[1])[t] = bzero8();

  // ---- loop-invariant registers ----
  bf16x8 bfrag[4][4];
#pragma unroll
  for (int g = 0; g < 4; ++g)
#pragma unroll
    for (int kk = 0; kk < 4; ++kk)
      bfrag[g][kk] = *(const bf16x8*)(Wn + (g * 64 + c) * 128 + kk * 32 + lq * 8);
  float bq[4];
#pragma unroll
  for (int g = 0; g < 4; ++g) bq[g] = bias[g * 64 + c] * LOG2E;
  ushort4 hmpA[4], hmpB[4];  // tile A = row r0+1, tile B = row r0 (this wave's px half)
  float lcA[4], lcB[4];
#pragma unroll
  for (int j = 0; j < 4; ++j) {
    int w = wb_ + lq * 4 + j;
    hmpA[j] = hmap2[(size_t)((b * 32 + r0 + 1) * 32 + w) * 64 + c];
    hmpB[j] = hmap2[(size_t)((b * 32 + r0) * 32 + w) * 64 + c];
    lcA[j] = 0.0f;
    lcB[j] = 0.0f;
  }

  const unsigned* pBelow = prodFlag + (size_t)(blk - 32) * 32;
  const unsigned* cAbove = consFlag + (size_t)(blk + 32) * 32;
  unsigned* myProd = prodFlag + (size_t)blk * 32;
  unsigned* myCons = consFlag + (size_t)blk * 32;

  const int wsrc = wb_ + l15 + dw;
  const bool oob = (unsigned)wsrc >= 32u;
  const int wc = wsrc & 31;
  const int swz = (wc & 7) << 4;

  __syncthreads();

#pragma unroll 1
  for (int s = 0; s < 32; ++s) {
    bf16* curb = buf[s & 1];
    bf16* nxtb = buf[(s + 1) & 1];
    const bool consume = (tl > 0) && (s > 0);
    const bool publish = (tl < 15) && (s < 31);
    bf16* slotOut = ring + (size_t)(((s & 7) * 512) + blk) * 2048;

    // ---- ring-slot reuse guard (steady state: never blocks) ----
    if (publish && s >= 8) {
      const unsigned tgt = (unsigned)(s - 7);
      while (__hip_atomic_load(cAbove, __ATOMIC_RELAXED, SCOPE_AGENT) < tgt)
        __builtin_amdgcn_s_sleep(1);
    }

    // ---- phase A: tile ms = 2+mhalf (row r0+1; reads curb rows 1,2) ----
    {
      f32x4 acc[4];
      const f32x4 fz = {0.f, 0.f, 0.f, 0.f};
#pragma unroll
      for (int g = 0; g < 4; ++g) acc[g] = fz;
#pragma unroll
      for (int kk = 0; kk < 4; ++kk) {
        const int srcr = 1 + (kk >> 1);
        const int c0 = (kk & 1) * 32 + lq * 8;
        int aoff = ((srcr * 32 + wc) * 128 + c0 * 2) ^ swz;
        bf16x8 a = *(const bf16x8*)((const char*)curb + aoff);
        if (oob) a = bzero8();
#pragma unroll
        for (int g = 0; g < 4; ++g)
          acc[g] = __builtin_amdgcn_mfma_f32_16x16x32_bf16(a, bfrag[g][kk], acc[g], 0, 0, 0);
      }
#pragma unroll
      for (int j = 0; j < 4; ++j) {
        const int w = wb_ + lq * 4 + j;
        ushort4 hm = hmpA[j];
        float e0 = __builtin_amdgcn_exp2f(-(acc[0][j] + bu2f(hm.x) + bq[0]));
        float e1 = __builtin_amdgcn_exp2f(-(acc[1][j] + bu2f(hm.y) + bq[1]));
        float e2 = __builtin_amdgcn_exp2f(-(acc[2][j] + bu2f(hm.z) + bq[2]));
        float e3 = __builtin_amdgcn_exp2f(-(acc[3][j] + bu2f(hm.w) + bq[3]));
        float fg = __builtin_amdgcn_rcpf(1.0f + e1);
        float igg = __builtin_amdgcn_rcpf((1.0f + e2) * (1.0f + e3));
        float lcv = fg * lcA[j] + K2E * igg;  // lc scaled by 2*log2e
        lcA[j] = lcv;
        float ey = __builtin_amdgcn_exp2f(-lcv);
        float lh = (1.0f - ey) * __builtin_amdgcn_rcpf((1.0f + e0) * (1.0f + ey));
        bf16 vb = (bf16)lh;
        int woff = ((2 * 32 + w) * 128 + c * 2) ^ ((w & 7) << 4);
        *(bf16*)((char*)nxtb + woff) = vb;
        if (publish) {
          unsigned u = (unsigned)__builtin_bit_cast(unsigned short, vb);
          unsigned pv = (unsigned)__shfl_xor((int)u, 1);
          if ((l & 1) == 0) {
            unsigned dword = u | (pv << 16);
            __hip_atomic_store((unsigned*)(slotOut + w * 64 + (c & ~1)), dword,
                               __ATOMIC_RELAXED, SCOPE_AGENT);
          }
        }
      }
    }
    __syncthreads();  // drains ring stores + nxtb row-2 LDS writes
    if (publish && t == 0)
      __hip_atomic_store(myProd, (unsigned)(s + 1), __ATOMIC_RELAXED, SCOPE_AGENT);

    // ---- phase B: acquire halo into curb row 0, then tile ms = mhalf ----
    if (consume) {
      const unsigned tgt = (unsigned)s;
      while (__hip_atomic_load(pBelow, __ATOMIC_RELAXED, SCOPE_AGENT) < tgt)
        __builtin_amdgcn_s_sleep(1);
      if (t < 256) {
        const bf16* slotIn =
            ring + (size_t)((((s - 1) & 7) * 512) + (blk - 32)) * 2048;
        int w = t >> 3, c8 = t & 7;
        const unsigned long long* src =
            (const unsigned long long*)(slotIn + w * 64 + c8 * 8);
        unsigned long long d0 = __hip_atomic_load(src, __ATOMIC_RELAXED, SCOPE_AGENT);
        unsigned long long d1 = __hip_atomic_load(src + 1, __ATOMIC_RELAXED, SCOPE_AGENT);
        int off = (w * 128 + c8 * 16) ^ ((w & 7) << 4);
        *(unsigned long long*)((char*)curb + off) = d0;
        *(unsigned long long*)((char*)curb + off + 8) = d1;
      }
    }
    __syncthreads();  // halo visible
    if (consume && t == 0)
      __hip_atomic_store(myCons, (unsigned)s, __ATOMIC_RELAXED, SCOPE_AGENT);

    {
      f32x4 acc[4];
      const f32x4 fz = {0.f, 0.f, 0.f, 0.f};
#pragma unroll
      for (int g = 0; g < 4; ++g) acc[g] = fz;
#pragma unroll
      for (int kk = 0; kk < 4; ++kk) {
        const int srcr = kk >> 1;
        const int c0 = (kk & 1) * 32 + lq * 8;
        int aoff = ((srcr * 32 + wc) * 128 + c0 * 2) ^ swz;
        bf16x8 a = *(const bf16x8*)((const char*)curb + aoff);
        if (oob) a = bzero8();
#pragma unroll
        for (int g = 0; g < 4; ++g)
          acc[g] = __builtin_amdgcn_mfma_f32_16x16x32_bf16(a, bfrag[g][kk], acc[g], 0, 0, 0);
      }
#pragma unroll
      for (int j = 0; j < 4; ++j) {
        const int w = wb_ + lq * 4 + j;
        ushort4 hm = hmpB[j];
        float e0 = __builtin_amdgcn_exp2f(-(acc[0][j] + bu2f(hm.x) + bq[0]));
        float e1 = __builtin_amdgcn_exp2f(-(acc[1][j] + bu2f(hm.y) + bq[1]));
        float e2 = __builtin_amdgcn_exp2f(-(acc[2][j] + bu2f(hm.z) + bq[2]));
        float e3 = __builtin_amdgcn_exp2f(-(acc[3][j] + bu2f(hm.w) + bq[3]));
        float fg = __builtin_amdgcn_rcpf(1.0f + e1);
        float igg = __builtin_amdgcn_rcpf((1.0f + e2) * (1.0f + e3));
        float lcv = fg * lcB[j] + K2E * igg;
        lcB[j] = lcv;
        float ey = __builtin_amdgcn_exp2f(-lcv);
        float lh = (1.0f - ey) * __builtin_amdgcn_rcpf((1.0f + e0) * (1.0f + ey));
        int woff = ((1 * 32 + w) * 128 + c * 2) ^ ((w & 7) << 4);
        *(bf16*)((char*)nxtb + woff) = (bf16)lh;
      }
    }
    __syncthreads();  // nxtb complete before next phase A
  }

  // ---- final writeback: rows 1,2 of buf[0] (step 31 wrote buf[0]) ----
  {
    int R = 1 + (t >> 8), rem = t & 255;
    int w = rem >> 3, c8 = rem & 7;
    int off = ((R * 32 + w) * 128 + c8 * 16) ^ ((w & 7) << 4);
    bf16x8 v = *(const bf16x8*)((const char*)buf[0] + off);
    *(bf16x8*)(lout + (size_t)((b * 32 + r0 + R - 1) * 32 + w) * 64 + c8 * 8) = v;
  }
}

// ---------------- final: out = x + (lhL + shift_down(lhR)) @ w_skip^T + b ----------------
__global__ __launch_bounds__(256, 2)
void final_kernel(const float* __restrict__ x, const bf16* __restrict__ lhL,
                  const bf16* __restrict__ lhR, const bf16* __restrict__ Wn,
                  const float* __restrict__ b_skip, float* __restrict__ out) {
  __shared__ __align__(16) bf16 At[64 * 64];
  __shared__ __align__(16) float smemT[128 * 72];  // [o2][m], padded rows
  const int tile = blockIdx.x;
  const int b = tile >> 4, h0 = (tile & 15) << 1;
  const int t = threadIdx.x;
#pragma unroll
  for (int i = 0; i < 2; ++i) {
    int idx = t + 256 * i;  // [0,512)
    int m = idx >> 3, c8 = idx & 7;
    int h = h0 + (m >> 5), w = m & 31;
    size_t p = (size_t)(b * 32 + h) * 32 + w;
    bf16x8 vL = *(const bf16x8*)(lhL + p * 64 + c8 * 8);
    bf16x8 v;
    if (h > 0) {
      bf16x8 vR = *(const bf16x8*)(lhR + (p - 32) * 64 + c8 * 8);
#pragma unroll
      for (int e = 0; e < 8; ++e) v[e] = (bf16)((float)vL[e] + (float)vR[e]);
    } else {
      v = vL;
    }
    int kb = (c8 * 16) ^ ((m & 7) << 4);
    *(bf16x8*)((char*)At + m * 128 + kb) = v;
  }
  __syncthreads();
  const int wv = t >> 6, l = t & 63;
  const int l15 = l & 15, lq = l >> 4;
  const int c = wv * 16 + l15;
  bf16x8 bfrag[2][2];
#pragma unroll
  for (int g = 0; g < 2; ++g)
#pragma unroll
    for (int kk = 0; kk < 2; ++kk)
      bfrag[g][kk] = *(const bf16x8*)(Wn + (g * 64 + c) * 64 + kk * 32 + lq * 8);
  f32x4 acc[4][2];
  const f32x4 fz = {0.f, 0.f, 0.f, 0.f};
#pragma unroll
  for (int ms = 0; ms < 4; ++ms)
#pragma unroll
    for (int g = 0; g < 2; ++g) acc[ms][g] = fz;
#pragma unroll
  for (int kk = 0; kk < 2; ++kk) {
#pragma unroll
    for (int ms = 0; ms < 4; ++ms) {
      int m = ms * 16 + l15;
      int kb = ((kk * 32 + lq * 8) * 2) ^ ((m & 7) << 4);
      bf16x8 a = *(const bf16x8*)((const char*)At + m * 128 + kb);
#pragma unroll
      for (int g = 0; g < 2; ++g)
        acc[ms][g] =
            __builtin_amdgcn_mfma_f32_16x16x32_bf16(a, bfrag[g][kk], acc[ms][g], 0, 0, 0);
    }
  }
  float bsk[2];
#pragma unroll
  for (int g = 0; g < 2; ++g) bsk[g] = b_skip[g * 64 + c];
#pragma unroll
  for (int ms = 0; ms < 4; ++ms)
#pragma unroll
    for (int g = 0; g < 2; ++g)
#pragma unroll
      for (int j = 0; j < 4; ++j) {
        int m = ms * 16 + lq * 4 + j;
        int n = g * 64 + c;
        smemT[n * 72 + m] = acc[ms][g][j] + bsk[g];
      }
  __syncthreads();
  const float* xb = x + (size_t)(b * 128) * 1024 + h0 * 32;
  float* ob = out + (size_t)(b * 128) * 1024 + h0 * 32;
#pragma unroll
  for (int i = 0; i < 8; ++i) {
    int idx = t + 256 * i;  // [0,2048)
    int o2 = idx >> 4, m4 = idx & 15;
    f32x4 s = *(const f32x4*)(&smemT[o2 * 72 + m4 * 4]);
    f32x4 xv = *(const f32x4*)(xb + (size_t)o2 * 1024 + m4 * 4);
#pragma unroll
    for (int e = 0; e < 4; ++e) s[e] += xv[e];
    *(f32x4*)(ob + (size_t)o2 * 1024 + m4 * 4) = s;
  }
}

extern "C" void kernel_launch(void* const* d_in, const int* in_sizes, int n_in,
                              void* d_out, int out_size, void* d_ws, size_t ws_size,
                              hipStream_t stream) {
  const float* x       = (const float*)d_in[0];
  const float* w_i2s   = (const float*)d_in[1];
  const float* w_left  = (const float*)d_in[2];
  const float* b_left  = (const float*)d_in[3];
  const float* w_right = (const float*)d_in[4];
  const float* b_right = (const float*)d_in[5];
  const float* w_skip  = (const float*)d_in[6];
  const float* b_skip  = (const float*)d_in[7];
  float* out = (float*)d_out;
  char* ws = (char*)d_ws;

  // ws layout (bytes); total ~29.8 MB
  bf16*     lhL   = (bf16*)(ws + 0x0000000);     // 2 MB
  bf16*     lhR   = (bf16*)(ws + 0x0200000);     // 2 MB
  ushort4*  hmap2 = (ushort4*)(ws + 0x0400000);  // 8 MB
  bf16*     ring  = (bf16*)(ws + 0x0C00000);     // 16 MB (8 slots x 512 x 4KB)
  unsigned* prodF = (unsigned*)(ws + 0x1C00000); // 64 KB (zeroed)
  unsigned* consF = (unsigned*)(ws + 0x1C10000); // 64 KB (zeroed)
  bf16*     WnI   = (bf16*)(ws + 0x1C20000);     // 64 KB
  bf16*     WnL   = (bf16*)(ws + 0x1C30000);
  bf16*     WnR   = (bf16*)(ws + 0x1C40000);
  bf16*     WnS   = (bf16*)(ws + 0x1C50000);

  // zero only the sync flags (128 KB) -- ring is flag-guarded
  hipMemsetAsync(ws + 0x1C00000, 0, 0x20000, stream);
  prep_kernel<<<128, 256, 0, stream>>>(w_i2s, w_left, w_right, w_skip, WnI, WnL, WnR, WnS);
  hmap_kernel<<<256, 256, 0, stream>>>(x, WnI, hmap2);
  scan_kernel<<<512, 512, 0, stream>>>(lhL, lhR, hmap2, WnL, WnR,
                                       b_left, b_right, ring, prodF, consF);
  final_kernel<<<256, 256, 0, stream>>>(x, lhL, lhR, WnS, b_skip, out);
}

// Round 11
// 173.867 us; speedup vs baseline: 2.4011x; 2.4011x over previous
//
#include <hip/hip_runtime.h>

// BiLSTM (diagonal, PixelRNN-style) on MI355X.
// R10: R9's 8-wave split (512-thread blocks, per-lane work halved vs R8) with
// the register pressure FIXED: hmap lives in LDS (staged once, 32KB), biases
// folded into hmap at pack time (two biased copies, one per stream), so the
// persistent per-thread state (~82 VGPR + acc) fits the 128-VGPR cap that
// 2-blocks/CU co-residency requires. R9's 64-VGPR spill storm (FETCH 613MB)
// should disappear. Ring depth 4, same fence-free LLC protocol as R8/R9.

using bf16   = __bf16;
using bf16x8 = __attribute__((ext_vector_type(8))) __bf16;
using f32x4  = __attribute__((ext_vector_type(4))) float;

#define SCOPE_AGENT __HIP_MEMORY_SCOPE_AGENT
#define LOG2E 1.4426950408889634f
#define K2E   2.8853900817779268f  // 2*log2e

__device__ __forceinline__ bf16x8 bzero8() {
  bf16x8 v;
#pragma unroll
  for (int e = 0; e < 8; ++e) v[e] = (bf16)0.0f;
  return v;
}
__device__ __forceinline__ unsigned short f2bu(float f) {
  bf16 b = (bf16)f;
  return __builtin_bit_cast(unsigned short, b);
}
__device__ __forceinline__ float bu2f(unsigned short u) {
  return __uint_as_float(((unsigned)u) << 16);
}

// ---------------- prep: weights -> bf16, [n][k] layouts ----------------
// WnL/WnR prescaled by log2e (gate math runs in exp2 space).
__global__ void prep_kernel(const float* __restrict__ w_i2s,
                            const float* __restrict__ w_left,
                            const float* __restrict__ w_right,
                            const float* __restrict__ w_skip,
                            bf16* __restrict__ WnI, bf16* __restrict__ WnL,
                            bf16* __restrict__ WnR, bf16* __restrict__ WnS) {
  int t = blockIdx.x * 256 + threadIdx.x;
  if (t < 32768) {
    WnI[t] = (bf16)w_i2s[t];  // [256][128] o-major == desired [n][k]
    int o = t >> 7, k = t & 127;
    int src = (k < 64) ? (o * 128 + k * 2) : (o * 128 + (k - 64) * 2 + 1);
    WnL[t] = (bf16)(w_left[src] * LOG2E);
    WnR[t] = (bf16)(w_right[src] * LOG2E);
    if (t < 8192) WnS[t] = (bf16)w_skip[t];  // [128][64]
  }
}

// -- hmapX = pack(log2e * (x @ w_i2s^T + bX)) : [p][c] ushort4, per stream --
__global__ __launch_bounds__(256, 2)
void hmap_kernel(const float* __restrict__ x, const bf16* __restrict__ Wn,
                 const float* __restrict__ bL, const float* __restrict__ bR,
                 ushort4* __restrict__ hmapL, ushort4* __restrict__ hmapR) {
  __shared__ __align__(16) bf16 At[64 * 128];  // XOR-swizzled
  const int tile = blockIdx.x;
  const int b = tile >> 4, h0 = (tile & 15) << 1;
  const int t = threadIdx.x;
  const float* xb = x + (size_t)(b * 128) * 1024 + h0 * 32;
#pragma unroll
  for (int i = 0; i < 8; ++i) {
    int idx = t + 256 * i;          // [0,2048)
    int cc = idx >> 4, m4 = idx & 15;
    f32x4 v = *(const f32x4*)(xb + (size_t)cc * 1024 + m4 * 4);
#pragma unroll
    for (int e = 0; e < 4; ++e) {
      int m = m4 * 4 + e;
      int kb = (cc * 2) ^ ((m & 7) << 4);
      *(bf16*)((char*)At + m * 256 + kb) = (bf16)v[e];
    }
  }
  __syncthreads();
  const int wv = t >> 6, l = t & 63;
  const int l15 = l & 15, lq = l >> 4;
  const int c = wv * 16 + l15;
  bf16x8 bfrag[4][4];
#pragma unroll
  for (int g = 0; g < 4; ++g)
#pragma unroll
    for (int kk = 0; kk < 4; ++kk)
      bfrag[g][kk] = *(const bf16x8*)(Wn + (g * 64 + c) * 128 + kk * 32 + lq * 8);
  float blq[4], brq[4];
#pragma unroll
  for (int g = 0; g < 4; ++g) {
    blq[g] = bL[g * 64 + c] * LOG2E;
    brq[g] = bR[g * 64 + c] * LOG2E;
  }
  f32x4 acc[4][4];
  const f32x4 fz = {0.f, 0.f, 0.f, 0.f};
#pragma unroll
  for (int ms = 0; ms < 4; ++ms)
#pragma unroll
    for (int g = 0; g < 4; ++g) acc[ms][g] = fz;
#pragma unroll
  for (int kk = 0; kk < 4; ++kk) {
#pragma unroll
    for (int ms = 0; ms < 4; ++ms) {
      int m = ms * 16 + l15;
      int kb = ((kk * 32 + lq * 8) * 2) ^ ((m & 7) << 4);
      bf16x8 a = *(const bf16x8*)((const char*)At + m * 256 + kb);
#pragma unroll
      for (int g = 0; g < 4; ++g)
        acc[ms][g] =
            __builtin_amdgcn_mfma_f32_16x16x32_bf16(a, bfrag[g][kk], acc[ms][g], 0, 0, 0);
    }
  }
  const int pix0 = tile * 64;
#pragma unroll
  for (int ms = 0; ms < 4; ++ms)
#pragma unroll
    for (int j = 0; j < 4; ++j) {
      int p = pix0 + ms * 16 + lq * 4 + j;
      ushort4 hl, hr;
      float a0 = acc[ms][0][j] * LOG2E, a1 = acc[ms][1][j] * LOG2E;
      float a2 = acc[ms][2][j] * LOG2E, a3 = acc[ms][3][j] * LOG2E;
      hl.x = f2bu(a0 + blq[0]); hl.y = f2bu(a1 + blq[1]);
      hl.z = f2bu(a2 + blq[2]); hl.w = f2bu(a3 + blq[3]);
      hr.x = f2bu(a0 + brq[0]); hr.y = f2bu(a1 + brq[1]);
      hr.z = f2bu(a2 + brq[2]); hr.w = f2bu(a3 + brq[3]);
      hmapL[(size_t)p * 64 + c] = hl;
      hmapR[(size_t)p * 64 + c] = hr;
    }
}

// ---------------- persistent scan: all 32 steps, 8-wave blocks ----------------
// blk = tl*32 + q, q = batch*2 + stream. Block owns rows {2tl, 2tl+1}.
// 8 waves: wave w -> channel group (w&3), m-half (w>>2).
// Phase A: tile ms = 2+(w>>2) (row r0+1, no halo) + publish; phase B: ms = w>>2.
// hmap (bias-folded, exp2-scaled) lives in LDS; lc in registers.
__global__ __launch_bounds__(512, 4)
void scan_kernel(bf16* __restrict__ lhLout, bf16* __restrict__ lhRout,
                 const ushort4* __restrict__ hmapL,
                 const ushort4* __restrict__ hmapR,
                 const bf16* __restrict__ WnL, const bf16* __restrict__ WnR,
                 bf16* __restrict__ ring, unsigned* __restrict__ prodFlag,
                 unsigned* __restrict__ consFlag) {
  __shared__ __align__(16) bf16 buf[2][3 * 32 * 64];  // 2 x 12 KB
  __shared__ __align__(16) ushort4 hlds[64 * 64];     // 32 KB: [local_px][c]
  const int blk = blockIdx.x;
  const int q = blk & 31, tl = blk >> 5;
  const bool right = (q & 1) != 0;
  const int b = q >> 1;
  const int r0 = tl * 2;
  const int t = threadIdx.x;
  const int dw = right ? 1 : -1;
  bf16* __restrict__ lout = right ? lhRout : lhLout;
  const bf16* __restrict__ Wn = right ? WnR : WnL;
  const ushort4* __restrict__ hsrc =
      (right ? hmapR : hmapL) + (size_t)(b * 1024 + r0 * 32) * 64;
  const int w8 = t >> 6, l = t & 63, l15 = l & 15, lq = l >> 4;
  const int wv = w8 & 3, mhalf = w8 >> 2;
  const int c = wv * 16 + l15;   // channel this lane owns
  const int wb_ = mhalf * 16;    // px half this wave owns

  // stage hmap slice (64 px x 64 ushort4 = 32 KB, contiguous in global)
#pragma unroll
  for (int i = 0; i < 8; ++i) hlds[t + 512 * i] = hsrc[t + 512 * i];

  // zero buf[0] fully + buf[1] row0
#pragma unroll
  for (int i = 0; i < 2; ++i) {
    int idx = t + 512 * i;
    if (idx < 768) ((bf16x8*)buf[0])[idx] = bzero8();
  }
  if (t < 256) ((bf16x8*)buf[1])[t] = bzero8();

  // ---- loop-invariant registers ----
  bf16x8 bfrag[4][4];
#pragma unroll
  for (int g = 0; g < 4; ++g)
#pragma unroll
    for (int kk = 0; kk < 4; ++kk)
      bfrag[g][kk] = *(const bf16x8*)(Wn + (g * 64 + c) * 128 + kk * 32 + lq * 8);
  float lcA[4], lcB[4];
#pragma unroll
  for (int j = 0; j < 4; ++j) {
    lcA[j] = 0.0f;
    lcB[j] = 0.0f;
  }

  const unsigned* pBelow = prodFlag + (size_t)(blk - 32) * 32;
  const unsigned* cAbove = consFlag + (size_t)(blk + 32) * 32;
  unsigned* myProd = prodFlag + (size_t)blk * 32;
  unsigned* myCons = consFlag + (size_t)blk * 32;

  const int wsrc = wb_ + l15 + dw;
  const bool oob = (unsigned)wsrc >= 32u;
  const int wc = wsrc & 31;
  const int swz = (wc & 7) << 4;

  __syncthreads();

#pragma unroll 1
  for (int s = 0; s < 32; ++s) {
    bf16* curb = buf[s & 1];
    bf16* nxtb = buf[(s + 1) & 1];
    const bool consume = (tl > 0) && (s > 0);
    const bool publish = (tl < 15) && (s < 31);
    bf16* slotOut = ring + (size_t)(((s & 3) * 512) + blk) * 2048;

    // ---- ring-slot reuse guard (depth 4; steady state: never blocks) ----
    if (publish && s >= 4) {
      const unsigned tgt = (unsigned)(s - 3);
      while (__hip_atomic_load(cAbove, __ATOMIC_RELAXED, SCOPE_AGENT) < tgt)
        __builtin_amdgcn_s_sleep(1);
    }

    // ---- phase A: tile ms = 2+mhalf (row r0+1; reads curb rows 1,2) ----
    {
      f32x4 acc[4];
      const f32x4 fz = {0.f, 0.f, 0.f, 0.f};
#pragma unroll
      for (int g = 0; g < 4; ++g) acc[g] = fz;
#pragma unroll
      for (int kk = 0; kk < 4; ++kk) {
        const int srcr = 1 + (kk >> 1);
        const int c0 = (kk & 1) * 32 + lq * 8;
        int aoff = ((srcr * 32 + wc) * 128 + c0 * 2) ^ swz;
        bf16x8 a = *(const bf16x8*)((const char*)curb + aoff);
        if (oob) a = bzero8();
#pragma unroll
        for (int g = 0; g < 4; ++g)
          acc[g] = __builtin_amdgcn_mfma_f32_16x16x32_bf16(a, bfrag[g][kk], acc[g], 0, 0, 0);
      }
#pragma unroll
      for (int j = 0; j < 4; ++j) {
        const int w = wb_ + lq * 4 + j;
        ushort4 hm = hlds[(32 + w) * 64 + c];
        float e0 = __builtin_amdgcn_exp2f(-(acc[0][j] + bu2f(hm.x)));
        float e1 = __builtin_amdgcn_exp2f(-(acc[1][j] + bu2f(hm.y)));
        float e2 = __builtin_amdgcn_exp2f(-(acc[2][j] + bu2f(hm.z)));
        float e3 = __builtin_amdgcn_exp2f(-(acc[3][j] + bu2f(hm.w)));
        float fg = __builtin_amdgcn_rcpf(1.0f + e1);
        float igg = __builtin_amdgcn_rcpf((1.0f + e2) * (1.0f + e3));
        float lcv = fg * lcA[j] + K2E * igg;  // lc scaled by 2*log2e
        lcA[j] = lcv;
        float ey = __builtin_amdgcn_exp2f(-lcv);
        float lh = (1.0f - ey) * __builtin_amdgcn_rcpf((1.0f + e0) * (1.0f + ey));
        bf16 vb = (bf16)lh;
        int woff = ((2 * 32 + w) * 128 + c * 2) ^ ((w & 7) << 4);
        *(bf16*)((char*)nxtb + woff) = vb;
        if (publish) {
          unsigned u = (unsigned)__builtin_bit_cast(unsigned short, vb);
          unsigned pv = (unsigned)__shfl_xor((int)u, 1);
          if ((l & 1) == 0) {
            unsigned dword = u | (pv << 16);
            __hip_atomic_store((unsigned*)(slotOut + w * 64 + (c & ~1)), dword,
                               __ATOMIC_RELAXED, SCOPE_AGENT);
          }
        }
      }
    }
    __syncthreads();  // drains ring stores + nxtb row-2 LDS writes
    if (publish && t == 0)
      __hip_atomic_store(myProd, (unsigned)(s + 1), __ATOMIC_RELAXED, SCOPE_AGENT);

    // ---- phase B: acquire halo into curb row 0, then tile ms = mhalf ----
    if (consume) {
      const unsigned tgt = (unsigned)s;
      while (__hip_atomic_load(pBelow, __ATOMIC_RELAXED, SCOPE_AGENT) < tgt)
        __builtin_amdgcn_s_sleep(1);
      if (t < 256) {
        const bf16* slotIn =
            ring + (size_t)((((s - 1) & 3) * 512) + (blk - 32)) * 2048;
        int w = t >> 3, c8 = t & 7;
        const unsigned long long* src =
            (const unsigned long long*)(slotIn + w * 64 + c8 * 8);
        unsigned long long d0 = __hip_atomic_load(src, __ATOMIC_RELAXED, SCOPE_AGENT);
        unsigned long long d1 = __hip_atomic_load(src + 1, __ATOMIC_RELAXED, SCOPE_AGENT);
        int off = (w * 128 + c8 * 16) ^ ((w & 7) << 4);
        *(unsigned long long*)((char*)curb + off) = d0;
        *(unsigned long long*)((char*)curb + off + 8) = d1;
      }
    }
    __syncthreads();  // halo visible
    if (consume && t == 0)
      __hip_atomic_store(myCons, (unsigned)s, __ATOMIC_RELAXED, SCOPE_AGENT);

    {
      f32x4 acc[4];
      const f32x4 fz = {0.f, 0.f, 0.f, 0.f};
#pragma unroll
      for (int g = 0; g < 4; ++g) acc[g] = fz;
#pragma unroll
      for (int kk = 0; kk < 4; ++kk) {
        const int srcr = kk >> 1;
        const int c0 = (kk & 1) * 32 + lq * 8;
        int aoff = ((srcr * 32 + wc) * 128 + c0 * 2) ^ swz;
        bf16x8 a = *(const bf16x8*)((const char*)curb + aoff);
        if (oob) a = bzero8();
#pragma unroll
        for (int g = 0; g < 4; ++g)
          acc[g] = __builtin_amdgcn_mfma_f32_16x16x32_bf16(a, bfrag[g][kk], acc[g], 0, 0, 0);
      }
#pragma unroll
      for (int j = 0; j < 4; ++j) {
        const int w = wb_ + lq * 4 + j;
        ushort4 hm = hlds[w * 64 + c];
        float e0 = __builtin_amdgcn_exp2f(-(acc[0][j] + bu2f(hm.x)));
        float e1 = __builtin_amdgcn_exp2f(-(acc[1][j] + bu2f(hm.y)));
        float e2 = __builtin_amdgcn_exp2f(-(acc[2][j] + bu2f(hm.z)));
        float e3 = __builtin_amdgcn_exp2f(-(acc[3][j] + bu2f(hm.w)));
        float fg = __builtin_amdgcn_rcpf(1.0f + e1);
        float igg = __builtin_amdgcn_rcpf((1.0f + e2) * (1.0f + e3));
        float lcv = fg * lcB[j] + K2E * igg;
        lcB[j] = lcv;
        float ey = __builtin_amdgcn_exp2f(-lcv);
        float lh = (1.0f - ey) * __builtin_amdgcn_rcpf((1.0f + e0) * (1.0f + ey));
        int woff = ((1 * 32 + w) * 128 + c * 2) ^ ((w & 7) << 4);
        *(bf16*)((char*)nxtb + woff) = (bf16)lh;
      }
    }
    __syncthreads();  // nxtb complete before next phase A
  }

  // ---- final writeback: rows 1,2 of buf[0] (step 31 wrote buf[0]) ----
  {
    int R = 1 + (t >> 8), rem = t & 255;
    int w = rem >> 3, c8 = rem & 7;
    int off = ((R * 32 + w) * 128 + c8 * 16) ^ ((w & 7) << 4);
    bf16x8 v = *(const bf16x8*)((const char*)buf[0] + off);
    *(bf16x8*)(lout + (size_t)((b * 32 + r0 + R - 1) * 32 + w) * 64 + c8 * 8) = v;
  }
}

// ---------------- final: out = x + (lhL + shift_down(lhR)) @ w_skip^T + b ----------------
__global__ __launch_bounds__(256, 2)
void final_kernel(const float* __restrict__ x, const bf16* __restrict__ lhL,
                  const bf16* __restrict__ lhR, const bf16* __restrict__ Wn,
                  const float* __restrict__ b_skip, float* __restrict__ out) {
  __shared__ __align__(16) bf16 At[64 * 64];
  __shared__ __align__(16) float smemT[128 * 72];  // [o2][m], padded rows
  const int tile = blockIdx.x;
  const int b = tile >> 4, h0 = (tile & 15) << 1;
  const int t = threadIdx.x;
#pragma unroll
  for (int i = 0; i < 2; ++i) {
    int idx = t + 256 * i;  // [0,512)
    int m = idx >> 3, c8 = idx & 7;
    int h = h0 + (m >> 5), w = m & 31;
    size_t p = (size_t)(b * 32 + h) * 32 + w;
    bf16x8 vL = *(const bf16x8*)(lhL + p * 64 + c8 * 8);
    bf16x8 v;
    if (h > 0) {
      bf16x8 vR = *(const bf16x8*)(lhR + (p - 32) * 64 + c8 * 8);
#pragma unroll
      for (int e = 0; e < 8; ++e) v[e] = (bf16)((float)vL[e] + (float)vR[e]);
    } else {
      v = vL;
    }
    int kb = (c8 * 16) ^ ((m & 7) << 4);
    *(bf16x8*)((char*)At + m * 128 + kb) = v;
  }
  __syncthreads();
  const int wv = t >> 6, l = t & 63;
  const int l15 = l & 15, lq = l >> 4;
  const int c = wv * 16 + l15;
  bf16x8 bfrag[2][2];
#pragma unroll
  for (int g = 0; g < 2; ++g)
#pragma unroll
    for (int kk = 0; kk < 2; ++kk)
      bfrag[g][kk] = *(const bf16x8*)(Wn + (g * 64 + c) * 64 + kk * 32 + lq * 8);
  f32x4 acc[4][2];
  const f32x4 fz = {0.f, 0.f, 0.f, 0.f};
#pragma unroll
  for (int ms = 0; ms < 4; ++ms)
#pragma unroll
    for (int g = 0; g < 2; ++g) acc[ms][g] = fz;
#pragma unroll
  for (int kk = 0; kk < 2; ++kk) {
#pragma unroll
    for (int ms = 0; ms < 4; ++ms) {
      int m = ms * 16 + l15;
      int kb = ((kk * 32 + lq * 8) * 2) ^ ((m & 7) << 4);
      bf16x8 a = *(const bf16x8*)((const char*)At + m * 128 + kb);
#pragma unroll
      for (int g = 0; g < 2; ++g)
        acc[ms][g] =
            __builtin_amdgcn_mfma_f32_16x16x32_bf16(a, bfrag[g][kk], acc[ms][g], 0, 0, 0);
    }
  }
  float bsk[2];
#pragma unroll
  for (int g = 0; g < 2; ++g) bsk[g] = b_skip[g * 64 + c];
#pragma unroll
  for (int ms = 0; ms < 4; ++ms)
#pragma unroll
    for (int g = 0; g < 2; ++g)
#pragma unroll
      for (int j = 0; j < 4; ++j) {
        int m = ms * 16 + lq * 4 + j;
        int n = g * 64 + c;
        smemT[n * 72 + m] = acc[ms][g][j] + bsk[g];
      }
  __syncthreads();
  const float* xb = x + (size_t)(b * 128) * 1024 + h0 * 32;
  float* ob = out + (size_t)(b * 128) * 1024 + h0 * 32;
#pragma unroll
  for (int i = 0; i < 8; ++i) {
    int idx = t + 256 * i;  // [0,2048)
    int o2 = idx >> 4, m4 = idx & 15;
    f32x4 s = *(const f32x4*)(&smemT[o2 * 72 + m4 * 4]);
    f32x4 xv = *(const f32x4*)(xb + (size_t)o2 * 1024 + m4 * 4);
#pragma unroll
    for (int e = 0; e < 4; ++e) s[e] += xv[e];
    *(f32x4*)(ob + (size_t)o2 * 1024 + m4 * 4) = s;
  }
}

extern "C" void kernel_launch(void* const* d_in, const int* in_sizes, int n_in,
                              void* d_out, int out_size, void* d_ws, size_t ws_size,
                              hipStream_t stream) {
  const float* x       = (const float*)d_in[0];
  const float* w_i2s   = (const float*)d_in[1];
  const float* w_left  = (const float*)d_in[2];
  const float* b_left  = (const float*)d_in[3];
  const float* w_right = (const float*)d_in[4];
  const float* b_right = (const float*)d_in[5];
  const float* w_skip  = (const float*)d_in[6];
  const float* b_skip  = (const float*)d_in[7];
  float* out = (float*)d_out;
  char* ws = (char*)d_ws;

  // ws layout (bytes); total ~29.8 MB
  bf16*     lhL   = (bf16*)(ws + 0x0000000);     // 2 MB
  bf16*     lhR   = (bf16*)(ws + 0x0200000);     // 2 MB
  ushort4*  hmapL = (ushort4*)(ws + 0x0400000);  // 8 MB (bias-folded, x log2e)
  ushort4*  hmapR = (ushort4*)(ws + 0x0C00000);  // 8 MB
  bf16*     ring  = (bf16*)(ws + 0x1400000);     // 8 MB (4 slots x 512 x 4KB)
  unsigned* prodF = (unsigned*)(ws + 0x1C00000); // 64 KB (zeroed)
  unsigned* consF = (unsigned*)(ws + 0x1C10000); // 64 KB (zeroed)
  bf16*     WnI   = (bf16*)(ws + 0x1C20000);     // 64 KB
  bf16*     WnL   = (bf16*)(ws + 0x1C30000);
  bf16*     WnR   = (bf16*)(ws + 0x1C40000);
  bf16*     WnS   = (bf16*)(ws + 0x1C50000);

  // zero only the sync flags (128 KB) -- ring is flag-guarded
  hipMemsetAsync(ws + 0x1C00000, 0, 0x20000, stream);
  prep_kernel<<<128, 256, 0, stream>>>(w_i2s, w_left, w_right, w_skip, WnI, WnL, WnR, WnS);
  hmap_kernel<<<256, 256, 0, stream>>>(x, WnI, b_left, b_right, hmapL, hmapR);
  scan_kernel<<<512, 512, 0, stream>>>(lhL, lhR, hmapL, hmapR, WnL, WnR,
                                       ring, prodF, consF);
  final_kernel<<<256, 256, 0, stream>>>(x, lhL, lhR, WnS, b_skip, out);
}